// Round 7
// baseline (115.062 us; speedup 1.0000x reference)
//
#include <hip/hip_runtime.h>

#define NBATCH 4096
#define NT 2048
#define NP 1024
#define NTH 256
#define EPT 8   // NT elements per thread
#define PPT 4   // NP items per thread
#define MSZ 1022          // interior system size (NP-2)
#define KT 4              // conv half-width: |rho|^5 ~ 1.4e-3 rel on M -> ~7e-6 on od
#define IMGW 14           // boundary image reach

__global__ __launch_bounds__(NTH, 4) void w2loss_kernel(
    const float* __restrict__ f,
    const float* __restrict__ obs,
    float* __restrict__ partial,
    unsigned* __restrict__ counter,
    float* __restrict__ out)
{
    __shared__ float sQ[NP];                      // q_k
    __shared__ float sM[NP];                      // M_k (2nd derivatives)
    __shared__ __align__(16) float sU[4096];      // union: rhs[1030] -> coeff float4[1023]
    __shared__ float sH[NTH];                     // prev-thread last square handoff
    __shared__ float sPow[IMGW];                  // rho^d
    __shared__ float sWSA[4], sWSB[4];
    __shared__ float sSqA[2], sSqB[2];
    __shared__ float sRed[4];
    __shared__ int   sWin;

    float* sRp = sU;                              // zero-padded rhs, KT+MSZ+KT = 1030
    float4* sCF = reinterpret_cast<float4*>(sU);  // per-knot (a,b,c,d), 1023 entries

    const int tid  = threadIdx.x;
    const int lane = tid & 63;
    const int wid  = tid >> 6;
    const int b    = blockIdx.x;
    const int base = tid * EPT;

    const float dt      = 0.001f;
    const float half_dt = 0.0005f;
    const float h       = 0.00097751710654936461f;  // 1/1023
    const float inv_h   = 1023.0f;
    const float inv_h2  = 1046529.0f;               // 1023^2
    const float h6      = h * (1.0f / 6.0f);
    const float ih6     = inv_h * (1.0f / 6.0f);

    const float* orow = obs + (size_t)b * NT;
    const float* frow = f   + (size_t)b * NT;
    float4 o0 = *reinterpret_cast<const float4*>(orow + base);
    float4 o1 = *reinterpret_cast<const float4*>(orow + base + 4);
    float4 g0 = *reinterpret_cast<const float4*>(frow + base);
    float4 g1 = *reinterpret_cast<const float4*>(frow + base + 4);

    if (tid < IMGW) {
        const float rho = -0.26794919243112270f;
        float v = 1.0f;
        for (int i = 0; i < tid; ++i) v *= rho;
        sPow[tid] = v;
    }
    if (tid < KT) { sRp[tid] = 0.0f; sRp[KT + MSZ + tid] = 0.0f; }

    // ---- squares + per-thread prefixes for BOTH rows ----
    float prefA[EPT], prefB[EPT];
    {
        float s0;
        s0 = o0.x*o0.x; prefA[0] = s0;
        s0 = o0.y*o0.y; prefA[1] = prefA[0] + s0;
        s0 = o0.z*o0.z; prefA[2] = prefA[1] + s0;
        s0 = o0.w*o0.w; prefA[3] = prefA[2] + s0;
        s0 = o1.x*o1.x; prefA[4] = prefA[3] + s0;
        s0 = o1.y*o1.y; prefA[5] = prefA[4] + s0;
        s0 = o1.z*o1.z; prefA[6] = prefA[5] + s0;
        s0 = o1.w*o1.w; prefA[7] = prefA[6] + s0;
        s0 = g0.x*g0.x; prefB[0] = s0;
        s0 = g0.y*g0.y; prefB[1] = prefB[0] + s0;
        s0 = g0.z*g0.z; prefB[2] = prefB[1] + s0;
        s0 = g0.w*g0.w; prefB[3] = prefB[2] + s0;
        s0 = g1.x*g1.x; prefB[4] = prefB[3] + s0;
        s0 = g1.y*g1.y; prefB[5] = prefB[4] + s0;
        s0 = g1.z*g1.z; prefB[6] = prefB[5] + s0;
        s0 = g1.w*g1.w; prefB[7] = prefB[6] + s0;
    }
    float sqA7 = o1.w * o1.w;
    float sqB7 = g1.w * g1.w;
    sH[tid] = sqA7;                      // handoff BEFORE B1 (read after B1)

    // ---- interleaved wave scans (2x ILP) ----
    float tsA = prefA[EPT - 1], tsB = prefB[EPT - 1];
    float wsA = tsA, wsB = tsB;
#pragma unroll
    for (int off = 1; off < 64; off <<= 1) {
        float uA = __shfl_up(wsA, off);
        float uB = __shfl_up(wsB, off);
        if (lane >= off) { wsA += uA; wsB += uB; }
    }
    if (lane == 63) { sWSA[wid] = wsA; sWSB[wid] = wsB; }
    if (tid == 0)       { sSqA[0] = prefA[0]; sSqB[0] = prefB[0]; }
    if (tid == NTH - 1) { sSqA[1] = sqA7;     sSqB[1] = sqB7; }
    __syncthreads();                                            // B1

    float exclA = wsA - tsA, exclB = wsB - tsB;
    if (wid > 0) { exclA += sWSA[0]; exclB += sWSB[0]; }
    if (wid > 1) { exclA += sWSA[1]; exclB += sWSB[1]; }
    if (wid > 2) { exclA += sWSA[2]; exclB += sWSB[2]; }
    float totA = sWSA[0] + sWSA[1] + sWSA[2] + sWSA[3];
    float totB = sWSB[0] + sWSB[1] + sWSB[2] + sWSB[3];
    float sq0A = sSqA[0], sq0B = sSqB[0];
    float invSA = 1.0f / (half_dt * (2.0f * totA - sSqA[1] - sq0A));
    float invSB = 1.0f / (half_dt * (2.0f * totB - sSqB[1] - sq0B));

    // ---- inverse-CDF by forward scatter: j claims p_k in (c_{j-1}, c_j] ----
    {
        float cm;
        if (tid == 0) cm = -1.0f;
        else {
            float sqprev = sH[tid - 1];
            cm = half_dt * (((exclA - sqprev) + exclA) - sq0A) * invSA;
        }
        float Pm = exclA;
#pragma unroll
        for (int e = 0; e < EPT; ++e) {
            int j = base + e;
            float Pj = exclA + prefA[e];
            float cc = (j == 0) ? 0.0f : half_dt * (Pm + Pj - sq0A) * invSA;
            int kLo = (int)floorf(cm * inv_h) + 1;
            int kHi = (int)floorf(cc * inv_h);
            if (kLo < 0) kLo = 0;
            if (j == NT - 1) kHi = NP - 1;          // guarantee k=1023 coverage
            else {
                if (e == EPT - 1) kHi += 1;         // bridge thread-boundary ulp gap
                if (kHi > NP - 1) kHi = NP - 1;
            }
            float qv = (float)j * dt;
            for (int k = kLo; k <= kHi; ++k) sQ[k] = qv;
            cm = cc;
            Pm = Pj;
        }
    }
    __syncthreads();                                            // B2

    // ---- rhs (strided, conflict-free) ----
#pragma unroll
    for (int kk = 0; kk < PPT; ++kk) {
        int i = tid + kk * NTH;
        if (i < MSZ)
            sRp[KT + i] = 6.0f * (sQ[i] - 2.0f * sQ[i + 1] + sQ[i + 2]) * inv_h2;
    }
    __syncthreads();                                            // B3

    // ---- tridiagonal solve: constant-tap conv + redundant boundary images ----
    {
        const float Cg = 0.28867513459481288f; // 1/(2*sqrt(3))
        const float CP[KT + 1] = {
            1.0f, -0.26794919243112270f, 0.071796769724490830f,
            -0.019237886466840586f, 0.0051547761428899979f };
#pragma unroll
        for (int kk = 0; kk < PPT; ++kk) {
            int i = tid + kk * NTH;
            if (i < MSZ) {
                float acc = 0.0f;
#pragma unroll
                for (int d = -KT; d <= KT; ++d) {
                    int ad = d < 0 ? -d : d;
                    acc += CP[ad] * sRp[KT + i + d];
                }
                if (i + 1 < IMGW) {
                    float t1 = 0.0f;
#pragma unroll
                    for (int k2 = 0; k2 < IMGW - 1; ++k2) t1 += sPow[k2 + 1] * sRp[KT + k2];
                    acc -= sPow[i + 1] * t1;
                }
                if (MSZ - i < IMGW) {
                    float t2 = 0.0f;
#pragma unroll
                    for (int k2 = MSZ - IMGW + 1; k2 < MSZ; ++k2) t2 += sPow[MSZ - k2] * sRp[KT + k2];
                    acc -= sPow[MSZ - i] * t2;
                }
                sM[i + 1] = Cg * acc;
            }
        }
    }
    if (tid == 0) { sM[0] = 0.0f; sM[NP - 1] = 0.0f; }
    __syncthreads();                                            // B4

    // ---- per-knot coefficient table (a,b,c,d) -> sCF (aliases sRp, dead now) ----
#pragma unroll
    for (int kk = 0; kk < PPT; ++kk) {
        int k = tid + kk * NTH;
        if (k < NP - 1) {
            float a  = sQ[k];
            float qn = sQ[k + 1];
            float Mk = sM[k];
            float Mn = sM[k + 1];
            float4 cf;
            cf.x = a;
            cf.y = (qn - a) * inv_h - (2.0f * Mk + Mn) * h6;
            cf.z = 0.5f * Mk;
            cf.w = (Mn - Mk) * ih6;
            sCF[k] = cf;
        }
    }
    __syncthreads();                                            // B5

    // ---- Phase B: F in registers, table-gather spline eval, integrate ----
    float local = 0.0f;
    float term0 = 0.0f, term7 = 0.0f;
    {
        const float c1B = half_dt * invSB;
        const float K0  = (2.0f * exclB - sq0B) * c1B;
        float tj = (float)base * dt;
#pragma unroll
        for (int e = 0; e < EPT; ++e) {
            float Gj = (e ? prefB[e - 1] : 0.0f) + prefB[e];
            float Fj = __builtin_fmaf(Gj, c1B, K0);   // exact 0 at j==0
            float sqe = e ? (prefB[e] - prefB[e - 1]) : prefB[0];
            float kf = Fj * inv_h;
            kf = fminf(fmaxf(kf, 0.0f), 1022.0f);
            int k = (int)kf;
            float s = __builtin_fmaf(-h, (float)k, Fj);
            float4 cf = sCF[k];
            float od = cf.x + s * (cf.y + s * (cf.z + s * cf.w));
            float dd = tj - od;
            float term = dd * dd * sqe;
            local += term;
            if (e == 0) term0 = term;
            if (e == EPT - 1) term7 = term;
            tj += dt;
        }
    }
    if (tid == 0)       local -= 0.5f * term0;   // trapezoid half-weight at j=0
    if (tid == NTH - 1) local -= 0.5f * term7;   // and at j=NT-1

#pragma unroll
    for (int off = 32; off > 0; off >>= 1) local += __shfl_down(local, off);
    if (lane == 0) sRed[wid] = local;
    __syncthreads();                                            // B6

    if (tid == 0) {
        partial[b] = (sRed[0] + sRed[1] + sRed[2] + sRed[3]) * (dt * invSB);
        __threadfence();
        unsigned old = atomicAdd(counter, 1u);
        sWin = (old == NBATCH - 1) ? 1 : 0;
    }
    __syncthreads();                                            // B7
    if (!sWin) return;

    // ---- last block: fixed-order deterministic final reduce ----
    __threadfence();
    float s = 0.0f;
#pragma unroll
    for (int i = 0; i < 16; i += 4) {
        float4 v = *reinterpret_cast<const float4*>(partial + tid * 16 + i);
        s += v.x + v.y + v.z + v.w;
    }
#pragma unroll
    for (int off = 32; off > 0; off >>= 1) s += __shfl_down(s, off);
    if (lane == 0) sRed[wid] = s;
    __syncthreads();                                            // B8
    if (tid == 0) out[0] = sRed[0] + sRed[1] + sRed[2] + sRed[3];
}

extern "C" void kernel_launch(void* const* d_in, const int* in_sizes, int n_in,
                              void* d_out, int out_size, void* d_ws, size_t ws_size,
                              hipStream_t stream) {
    const float* f   = (const float*)d_in[0];
    const float* obs = (const float*)d_in[1];
    float* out      = (float*)d_out;
    float* partial  = (float*)d_ws;                        // 4096 floats
    unsigned* counter = (unsigned*)((char*)d_ws + NBATCH * sizeof(float));

    hipMemsetAsync(counter, 0, sizeof(unsigned), stream);  // graph-safe, per-launch
    w2loss_kernel<<<NBATCH, NTH, 0, stream>>>(f, obs, partial, counter, out);
}

// Round 8
// 29.005 us; speedup vs baseline: 3.9669x; 3.9669x over previous
//
#include <hip/hip_runtime.h>

#define NBATCH 4096
#define NT 2048
#define NP 1024
#define NTH 256
#define EPT 8   // NT elements per thread
#define PPT 4   // NP items per thread
#define MSZ 1022          // interior system size (NP-2)
#define KT 4              // conv half-width: |rho|^5 ~ 1.4e-3 rel on M -> ~7e-6 on od
#define IMGW 14           // boundary image reach

__global__ __launch_bounds__(NTH, 4) void w2loss_kernel(
    const float* __restrict__ f,
    const float* __restrict__ obs,
    float* __restrict__ partial)
{
    __shared__ float sQ[NP];                      // q_k
    __shared__ float sM[NP];                      // M_k (2nd derivatives)
    __shared__ __align__(16) float sU[4096];      // union: rhs[1030] -> coeff float4[1023]
    __shared__ float sH[NTH];                     // prev-thread last square handoff
    __shared__ float sPow[IMGW];                  // rho^d
    __shared__ float sWSA[4], sWSB[4];
    __shared__ float sSqA[2], sSqB[2];
    __shared__ float sRed[4];

    float* sRp = sU;                              // zero-padded rhs, KT+MSZ+KT = 1030
    float4* sCF = reinterpret_cast<float4*>(sU);  // per-knot (a,b,c,d), 1023 entries

    const int tid  = threadIdx.x;
    const int lane = tid & 63;
    const int wid  = tid >> 6;
    const int b    = blockIdx.x;
    const int base = tid * EPT;

    const float dt      = 0.001f;
    const float half_dt = 0.0005f;
    const float h       = 0.00097751710654936461f;  // 1/1023
    const float inv_h   = 1023.0f;
    const float inv_h2  = 1046529.0f;               // 1023^2
    const float h6      = h * (1.0f / 6.0f);
    const float ih6     = inv_h * (1.0f / 6.0f);

    const float* orow = obs + (size_t)b * NT;
    const float* frow = f   + (size_t)b * NT;
    float4 o0 = *reinterpret_cast<const float4*>(orow + base);
    float4 o1 = *reinterpret_cast<const float4*>(orow + base + 4);
    float4 g0 = *reinterpret_cast<const float4*>(frow + base);
    float4 g1 = *reinterpret_cast<const float4*>(frow + base + 4);

    if (tid < IMGW) {
        const float rho = -0.26794919243112270f;
        float v = 1.0f;
        for (int i = 0; i < tid; ++i) v *= rho;
        sPow[tid] = v;
    }
    if (tid < KT) { sRp[tid] = 0.0f; sRp[KT + MSZ + tid] = 0.0f; }

    // ---- squares + per-thread prefixes for BOTH rows ----
    float prefA[EPT], prefB[EPT];
    {
        float s0;
        s0 = o0.x*o0.x; prefA[0] = s0;
        s0 = o0.y*o0.y; prefA[1] = prefA[0] + s0;
        s0 = o0.z*o0.z; prefA[2] = prefA[1] + s0;
        s0 = o0.w*o0.w; prefA[3] = prefA[2] + s0;
        s0 = o1.x*o1.x; prefA[4] = prefA[3] + s0;
        s0 = o1.y*o1.y; prefA[5] = prefA[4] + s0;
        s0 = o1.z*o1.z; prefA[6] = prefA[5] + s0;
        s0 = o1.w*o1.w; prefA[7] = prefA[6] + s0;
        s0 = g0.x*g0.x; prefB[0] = s0;
        s0 = g0.y*g0.y; prefB[1] = prefB[0] + s0;
        s0 = g0.z*g0.z; prefB[2] = prefB[1] + s0;
        s0 = g0.w*g0.w; prefB[3] = prefB[2] + s0;
        s0 = g1.x*g1.x; prefB[4] = prefB[3] + s0;
        s0 = g1.y*g1.y; prefB[5] = prefB[4] + s0;
        s0 = g1.z*g1.z; prefB[6] = prefB[5] + s0;
        s0 = g1.w*g1.w; prefB[7] = prefB[6] + s0;
    }
    float sqA7 = o1.w * o1.w;
    float sqB7 = g1.w * g1.w;
    sH[tid] = sqA7;                      // handoff BEFORE B1 (read after B1)

    // ---- interleaved wave scans (2x ILP) ----
    float tsA = prefA[EPT - 1], tsB = prefB[EPT - 1];
    float wsA = tsA, wsB = tsB;
#pragma unroll
    for (int off = 1; off < 64; off <<= 1) {
        float uA = __shfl_up(wsA, off);
        float uB = __shfl_up(wsB, off);
        if (lane >= off) { wsA += uA; wsB += uB; }
    }
    if (lane == 63) { sWSA[wid] = wsA; sWSB[wid] = wsB; }
    if (tid == 0)       { sSqA[0] = prefA[0]; sSqB[0] = prefB[0]; }
    if (tid == NTH - 1) { sSqA[1] = sqA7;     sSqB[1] = sqB7; }
    __syncthreads();                                            // B1

    float exclA = wsA - tsA, exclB = wsB - tsB;
    if (wid > 0) { exclA += sWSA[0]; exclB += sWSB[0]; }
    if (wid > 1) { exclA += sWSA[1]; exclB += sWSB[1]; }
    if (wid > 2) { exclA += sWSA[2]; exclB += sWSB[2]; }
    float totA = sWSA[0] + sWSA[1] + sWSA[2] + sWSA[3];
    float totB = sWSB[0] + sWSB[1] + sWSB[2] + sWSB[3];
    float sq0A = sSqA[0], sq0B = sSqB[0];
    float invSA = 1.0f / (half_dt * (2.0f * totA - sSqA[1] - sq0A));
    float invSB = 1.0f / (half_dt * (2.0f * totB - sSqB[1] - sq0B));

    // ---- inverse-CDF by forward scatter: j claims p_k in (c_{j-1}, c_j] ----
    {
        float cm;
        if (tid == 0) cm = -1.0f;
        else {
            float sqprev = sH[tid - 1];
            cm = half_dt * (((exclA - sqprev) + exclA) - sq0A) * invSA;
        }
        float Pm = exclA;
#pragma unroll
        for (int e = 0; e < EPT; ++e) {
            int j = base + e;
            float Pj = exclA + prefA[e];
            float cc = (j == 0) ? 0.0f : half_dt * (Pm + Pj - sq0A) * invSA;
            int kLo = (int)floorf(cm * inv_h) + 1;
            int kHi = (int)floorf(cc * inv_h);
            if (kLo < 0) kLo = 0;
            if (j == NT - 1) kHi = NP - 1;          // guarantee k=1023 coverage
            else {
                if (e == EPT - 1) kHi += 1;         // bridge thread-boundary ulp gap
                if (kHi > NP - 1) kHi = NP - 1;
            }
            float qv = (float)j * dt;
            for (int k = kLo; k <= kHi; ++k) sQ[k] = qv;
            cm = cc;
            Pm = Pj;
        }
    }
    __syncthreads();                                            // B2

    // ---- rhs (strided, conflict-free) ----
#pragma unroll
    for (int kk = 0; kk < PPT; ++kk) {
        int i = tid + kk * NTH;
        if (i < MSZ)
            sRp[KT + i] = 6.0f * (sQ[i] - 2.0f * sQ[i + 1] + sQ[i + 2]) * inv_h2;
    }
    __syncthreads();                                            // B3

    // ---- tridiagonal solve: constant-tap conv + redundant boundary images ----
    {
        const float Cg = 0.28867513459481288f; // 1/(2*sqrt(3))
        const float CP[KT + 1] = {
            1.0f, -0.26794919243112270f, 0.071796769724490830f,
            -0.019237886466840586f, 0.0051547761428899979f };
#pragma unroll
        for (int kk = 0; kk < PPT; ++kk) {
            int i = tid + kk * NTH;
            if (i < MSZ) {
                float acc = 0.0f;
#pragma unroll
                for (int d = -KT; d <= KT; ++d) {
                    int ad = d < 0 ? -d : d;
                    acc += CP[ad] * sRp[KT + i + d];
                }
                if (i + 1 < IMGW) {
                    float t1 = 0.0f;
#pragma unroll
                    for (int k2 = 0; k2 < IMGW - 1; ++k2) t1 += sPow[k2 + 1] * sRp[KT + k2];
                    acc -= sPow[i + 1] * t1;
                }
                if (MSZ - i < IMGW) {
                    float t2 = 0.0f;
#pragma unroll
                    for (int k2 = MSZ - IMGW + 1; k2 < MSZ; ++k2) t2 += sPow[MSZ - k2] * sRp[KT + k2];
                    acc -= sPow[MSZ - i] * t2;
                }
                sM[i + 1] = Cg * acc;
            }
        }
    }
    if (tid == 0) { sM[0] = 0.0f; sM[NP - 1] = 0.0f; }
    __syncthreads();                                            // B4

    // ---- per-knot coefficient table (a,b,c,d) -> sCF (aliases sRp, dead now) ----
#pragma unroll
    for (int kk = 0; kk < PPT; ++kk) {
        int k = tid + kk * NTH;
        if (k < NP - 1) {
            float a  = sQ[k];
            float qn = sQ[k + 1];
            float Mk = sM[k];
            float Mn = sM[k + 1];
            float4 cf;
            cf.x = a;
            cf.y = (qn - a) * inv_h - (2.0f * Mk + Mn) * h6;
            cf.z = 0.5f * Mk;
            cf.w = (Mn - Mk) * ih6;
            sCF[k] = cf;
        }
    }
    __syncthreads();                                            // B5

    // ---- Phase B: F in registers, table-gather spline eval, integrate ----
    float local = 0.0f;
    float term0 = 0.0f, term7 = 0.0f;
    {
        const float c1B = half_dt * invSB;
        const float K0  = (2.0f * exclB - sq0B) * c1B;
        float tj = (float)base * dt;
#pragma unroll
        for (int e = 0; e < EPT; ++e) {
            float Gj = (e ? prefB[e - 1] : 0.0f) + prefB[e];
            float Fj = __builtin_fmaf(Gj, c1B, K0);   // ~exact 0 at j==0
            float sqe = e ? (prefB[e] - prefB[e - 1]) : prefB[0];
            float kf = Fj * inv_h;
            kf = fminf(fmaxf(kf, 0.0f), 1022.0f);
            int k = (int)kf;
            float s = __builtin_fmaf(-h, (float)k, Fj);
            float4 cf = sCF[k];
            float od = cf.x + s * (cf.y + s * (cf.z + s * cf.w));
            float dd = tj - od;
            float term = dd * dd * sqe;
            local += term;
            if (e == 0) term0 = term;
            if (e == EPT - 1) term7 = term;
            tj += dt;
        }
    }
    if (tid == 0)       local -= 0.5f * term0;   // trapezoid half-weight at j=0
    if (tid == NTH - 1) local -= 0.5f * term7;   // and at j=NT-1

#pragma unroll
    for (int off = 32; off > 0; off >>= 1) local += __shfl_down(local, off);
    if (lane == 0) sRed[wid] = local;
    __syncthreads();                                            // B6
    if (tid == 0) partial[b] = (sRed[0] + sRed[1] + sRed[2] + sRed[3]) * (dt * invSB);
}

// fixed-order deterministic reduction of 4096 partials -> scalar
__global__ __launch_bounds__(NTH) void w2loss_reduce(
    const float* __restrict__ partial, float* __restrict__ out)
{
    __shared__ float sRed[4];
    const int tid  = threadIdx.x;
    const int lane = tid & 63;
    const int wid  = tid >> 6;
    float s = 0.0f;
#pragma unroll
    for (int i = 0; i < 16; i += 4) {
        float4 v = *reinterpret_cast<const float4*>(partial + tid * 16 + i);
        s += v.x + v.y + v.z + v.w;
    }
#pragma unroll
    for (int off = 32; off > 0; off >>= 1) s += __shfl_down(s, off);
    if (lane == 0) sRed[wid] = s;
    __syncthreads();
    if (tid == 0) out[0] = sRed[0] + sRed[1] + sRed[2] + sRed[3];
}

extern "C" void kernel_launch(void* const* d_in, const int* in_sizes, int n_in,
                              void* d_out, int out_size, void* d_ws, size_t ws_size,
                              hipStream_t stream) {
    const float* f   = (const float*)d_in[0];
    const float* obs = (const float*)d_in[1];
    float* out     = (float*)d_out;
    float* partial = (float*)d_ws;   // 4096 floats = 16 KB scratch

    w2loss_kernel<<<NBATCH, NTH, 0, stream>>>(f, obs, partial);
    w2loss_reduce<<<1, NTH, 0, stream>>>(partial, out);
}